// Round 11
// baseline (550.406 us; speedup 1.0000x reference)
//
#include <hip/hip_runtime.h>
#include <cstdint>

#define N_NODES 100000
#define N_EDGES 3200000
#define BSZ     64                // dst nodes per bucket
#define NBUCK   1563              // ceil(N_NODES / 64)
#define NPAD    (NBUCK * BSZ)     // 100032
#define NPAIR   (NPAD / 2)        // 50016 node-pairs for k5
#define SORTCAP 4096              // bucket avg 2048, std ~45 -> huge margin
#define K13_BLOCKS 256
#define K13_CHUNK  12500          // 256 * 12500 = 3.2M exactly
#define K5_BLOCKS  2048           // x4 waves = 8192 = full wave budget
#define K5_WAVES   (K5_BLOCKS * 4)

// ---- float <-> order-preserving unsigned (signed-float max via uint max) ----
__device__ __forceinline__ unsigned flipf(float f) {
    unsigned u = __float_as_uint(f);
    return (u & 0x80000000u) ? ~u : (u | 0x80000000u);   // never returns 0
}
__device__ __forceinline__ float unflipf(unsigned v) {
    unsigned u = (v & 0x80000000u) ? (v & 0x7FFFFFFFu) : ~v;
    return __uint_as_float(u);
}
__device__ __forceinline__ int2 nt_load_rec(const int2* p) {
    unsigned long long v = __builtin_nontemporal_load((const unsigned long long*)p);
    return make_int2((int)(unsigned)(v & 0xFFFFFFFFull), (int)(unsigned)(v >> 32));
}

// ---------------- K1: per-(block,bucket) counts, plain stores, NO global atomics ----------------
__global__ __launch_bounds__(1024) void k1_count(const int* __restrict__ dst,
                                                 int* __restrict__ cntMat) {
    __shared__ int hist[NBUCK];
    for (int t = threadIdx.x; t < NBUCK; t += 1024) hist[t] = 0;
    __syncthreads();
    int e0 = blockIdx.x * K13_CHUNK;
    for (int k = threadIdx.x; k < K13_CHUNK; k += 1024)
        atomicAdd(&hist[__builtin_nontemporal_load(&dst[e0 + k]) >> 6], 1);
    __syncthreads();
    int base = blockIdx.x * NBUCK;
    for (int t = threadIdx.x; t < NBUCK; t += 1024)
        cntMat[base + t] = hist[t];
}

// ---------------- K2: scan cntMat -> bucketBase + per-(block,bucket) blockBase ----------------
__global__ __launch_bounds__(1024) void k2_scan(const int* __restrict__ cntMat,
                                                int* __restrict__ blockBase,
                                                int* __restrict__ bucketBase) {
    __shared__ int part[1024];
    int t = threadIdx.x;
    int b0 = t * 2, b1 = t * 2 + 1;
    int c0 = 0, c1 = 0;
    if (b0 < NBUCK) for (int b = 0; b < K13_BLOCKS; b++) c0 += cntMat[b * NBUCK + b0];
    if (b1 < NBUCK) for (int b = 0; b < K13_BLOCKS; b++) c1 += cntMat[b * NBUCK + b1];
    int s = c0 + c1;
    part[t] = s;
    __syncthreads();
    for (int off = 1; off < 1024; off <<= 1) {
        int u = (t >= off) ? part[t - off] : 0;
        __syncthreads();
        part[t] += u;
        __syncthreads();
    }
    int ex = part[t] - s;
    int base0 = ex, base1 = ex + c0;
    if (b0 < NBUCK) bucketBase[b0] = base0;
    if (b1 < NBUCK) bucketBase[b1] = base1;
    if (t == 1023) bucketBase[NBUCK] = part[1023];       // == N_EDGES
    int run0 = base0, run1 = base1;
    for (int b = 0; b < K13_BLOCKS; b++) {
        if (b0 < NBUCK) { blockBase[b * NBUCK + b0] = run0; run0 += cntMat[b * NBUCK + b0]; }
        if (b1 < NBUCK) { blockBase[b * NBUCK + b1] = run1; run1 += cntMat[b * NBUCK + b1]; }
    }
}

// ---------------- K3: SINGLE-PASS scatter (bases precomputed, no re-count) ----------------
// record: int2 { (src<<6) | (dst&63), bits(norm) }
__global__ __launch_bounds__(1024) void k3_scatter(const int* __restrict__ ei,
                                                   const float* __restrict__ norm,
                                                   const int* __restrict__ blockBase,
                                                   int2* __restrict__ ebuf) {
    __shared__ int lcur[NBUCK];
    int mbase = blockIdx.x * NBUCK;
    for (int t = threadIdx.x; t < NBUCK; t += 1024) lcur[t] = blockBase[mbase + t];
    __syncthreads();
    int e0 = blockIdx.x * K13_CHUNK;
    for (int k = threadIdx.x; k < K13_CHUNK; k += 1024) {
        int e = e0 + k;
        int s = __builtin_nontemporal_load(&ei[e]);
        int d = __builtin_nontemporal_load(&ei[N_EDGES + e]);
        float w = __builtin_nontemporal_load(&norm[e]);
        int r = atomicAdd(&lcur[d >> 6], 1);
        ebuf[r] = make_int2((s << 6) | (d & 63), __float_as_int(w));
    }
}

// ---- K3b: per-bucket counting sort by dst node (2 global reads, 1 LDS buffer)
//      + FUSED layer-1 aggregation -> packed row (32 B/node, 3.2 MB table) ----
__global__ __launch_bounds__(256) void k3b_sort_agg(
        const float2* __restrict__ x, const int* __restrict__ bucketBase,
        int2* __restrict__ ebuf, int* __restrict__ nodeBase,
        float* __restrict__ packed) {
    __shared__ int2 srt[SORTCAP];            // 32 KB (only LDS buffer)
    __shared__ int cnt[BSZ], off_s[BSZ], cur[BSZ];
    __shared__ float    s_a0[BSZ], s_a1[BSZ];
    __shared__ unsigned s_m0[BSZ], s_m1[BSZ];
    int b = blockIdx.x;
    int beg = bucketBase[b], end = bucketBase[b + 1];
    int n = end - beg;
    if (threadIdx.x < BSZ) {
        cnt[threadIdx.x] = 0;
        s_a0[threadIdx.x] = 0.0f; s_a1[threadIdx.x] = 0.0f;
        s_m0[threadIdx.x] = 0u;   s_m1[threadIdx.x] = 0u;
    }
    __syncthreads();
    // pass 1: count (global read #1)
    for (int k = threadIdx.x; k < n; k += 256)
        atomicAdd(&cnt[ebuf[beg + k].x & 63], 1);
    __syncthreads();
    if (threadIdx.x == 0) {
        int a = 0;
        for (int j = 0; j < BSZ; j++) { off_s[j] = a; cur[j] = a; a += cnt[j]; }
    }
    __syncthreads();
    // pass 2: place into srt (global read #2, L2-hot) + aggregate on UNSORTED order
    // (sorted-order agg would serialize same-address LDS atomics)
    for (int k = threadIdx.x; k < n; k += 256) {
        int2 r = ebuf[beg + k];
        int l = r.x & 63;
        int p = atomicAdd(&cur[l], 1);
        srt[p] = r;
        float2 xs = x[r.x >> 6];             // 0.8 MB table, L2-resident
        float w = __int_as_float(r.y);
        atomicAdd(&s_a0[l], xs.x * w);
        atomicAdd(&s_a1[l], xs.y * w);
        atomicMax(&s_m0[l], flipf(xs.x));
        atomicMax(&s_m1[l], flipf(xs.y));
    }
    __syncthreads();
    // pass 3: write back sorted (coalesced)
    for (int k = threadIdx.x; k < n; k += 256) ebuf[beg + k] = srt[k];
    if (threadIdx.x < BSZ) nodeBase[b * BSZ + threadIdx.x] = beg + off_s[threadIdx.x];
    if (threadIdx.x == BSZ) nodeBase[b * BSZ + BSZ] = end;  // benign same-value race
    __syncthreads();

    int t = threadIdx.x;
    if (t >= BSZ) return;
    int i = b * BSZ + t;
    if (i >= N_NODES) return;
    float2 xi = x[i];
    unsigned m0u = s_m0[t], m1u = s_m1[t];
    float m0 = m0u ? unflipf(m0u) : 0.0f;    // 0 sentinel == empty segment -> 0
    float m1 = m1u ? unflipf(m1u) : 0.0f;
    float4* pk = (float4*)(packed + ((size_t)i << 3));
    pk[0] = make_float4(xi.x, xi.y, s_a0[t], s_a1[t]);
    pk[1] = make_float4(m0, m1, 0.0f, 0.0f);
}

// -------- K5: fused layer-2 MAX+SUM aggregation in h1-feature space --------
// Half-wave per node (lane f = feature), flat grid-stride, unroll 8.
// No atomics, plain stores. Grid sized to the full 8192-wave budget.
__global__ __launch_bounds__(256) void k5_agg(
        const float* __restrict__ packed, const int2* __restrict__ ebuf,
        const int* __restrict__ nodeBase,
        const float* __restrict__ w1m_l, const float* __restrict__ b1m,
        const float* __restrict__ w1m_r,
        const float* __restrict__ w1x_l, const float* __restrict__ b1x,
        const float* __restrict__ w1x_r,
        float* __restrict__ aggT) {
    int f = threadIdx.x & 31;
    float c0, c1, c2, c3, c4;
    int gsel;
    if (f < 24) {
        c0 = b1m[f];
        c1 = w1m_l[2 * f]; c2 = w1m_l[2 * f + 1];
        c3 = w1m_r[2 * f]; c4 = w1m_r[2 * f + 1];
        gsel = 2;                            // (a0,a1)
    } else {
        int g = f - 24;
        c0 = b1x[g];
        c1 = w1x_l[2 * g]; c2 = w1x_l[2 * g + 1];
        c3 = w1x_r[2 * g]; c4 = w1x_r[2 * g + 1];
        gsel = 4;                            // (m0,m1)
    }
    int h = (threadIdx.x >> 5) & 1;
    int wid = blockIdx.x * 4 + (threadIdx.x >> 6);

    for (int p = wid; p < NPAIR; p += K5_WAVES) {
        int i = 2 * p + h;
        int e0 = nodeBase[i], e1 = nodeBase[i + 1];
        float mx = 0.0f, sm = 0.0f;          // relu floor == empty-segment 0
        int e = e0;
        for (; e + 7 < e1; e += 8) {
            int2 rr[8];
#pragma unroll
            for (int j = 0; j < 8; j++) rr[j] = nt_load_rec(&ebuf[e + j]);
            float vv[8];
#pragma unroll
            for (int j = 0; j < 8; j++) {
                const float* row = packed + ((size_t)(rr[j].x >> 6) << 3);
                float2 xv = *(const float2*)row;
                float2 gv = *(const float2*)(row + gsel);
                vv[j] = fmaxf(c0 + c1 * gv.x + c2 * gv.y + c3 * xv.x + c4 * xv.y, 0.0f);
            }
#pragma unroll
            for (int j = 0; j < 8; j++) {
                mx = fmaxf(mx, vv[j]);
                sm = fmaf(__int_as_float(rr[j].y), vv[j], sm);
            }
        }
        for (; e < e1; e++) {
            int2 r = nt_load_rec(&ebuf[e]);
            const float* row = packed + ((size_t)(r.x >> 6) << 3);
            float2 xv = *(const float2*)row;
            float2 gv = *(const float2*)(row + gsel);
            float v = fmaxf(c0 + c1 * gv.x + c2 * gv.y + c3 * xv.x + c4 * xv.y, 0.0f);
            mx = fmaxf(mx, v);
            sm = fmaf(__int_as_float(r.y), v, sm);
        }
        float* o = aggT + ((size_t)i << 6);
        o[f] = mx;
        o[32 + f] = sm;
    }
}

// -------- K6: node-parallel final: W2m_l@sm + node2 + MLP head -> out --------
__global__ __launch_bounds__(256) void k6_final(
        const float* __restrict__ packed, const float* __restrict__ aggT,
        const float* __restrict__ w1m_l, const float* __restrict__ b1m,
        const float* __restrict__ w1m_r,
        const float* __restrict__ w1x_l, const float* __restrict__ b1x,
        const float* __restrict__ w1x_r,
        const float* __restrict__ w2m_l,
        const float* __restrict__ b2m, const float* __restrict__ w2m_r,
        const float* __restrict__ w2x_l, const float* __restrict__ b2x,
        const float* __restrict__ w2x_r,
        const float* __restrict__ w3, const float* __restrict__ b3,
        const float* __restrict__ w4, const float* __restrict__ b4,
        const float* __restrict__ w5, const float* __restrict__ b5,
        float* __restrict__ out) {
    __shared__ float sw[1387];
    for (int t = threadIdx.x; t < 1387; t += 256) {
        float v;
        if (t < 48)        v = w1m_l[t];
        else if (t < 72)   v = b1m[t - 48];
        else if (t < 120)  v = w1m_r[t - 72];
        else if (t < 136)  v = w1x_l[t - 120];
        else if (t < 144)  v = b1x[t - 136];
        else if (t < 160)  v = w1x_r[t - 144];
        else if (t < 544)  v = w2m_l[t - 160];
        else if (t < 556)  v = b2m[t - 544];
        else if (t < 940)  v = w2m_r[t - 556];
        else if (t < 1068) v = w2x_l[t - 940];
        else if (t < 1072) v = b2x[t - 1068];
        else if (t < 1200) v = w2x_r[t - 1072];
        else if (t < 1328) v = w3[t - 1200];
        else if (t < 1336) v = b3[t - 1328];
        else if (t < 1376) v = w4[t - 1336];
        else if (t < 1381) v = b4[t - 1376];
        else if (t < 1386) v = w5[t - 1381];
        else               v = b5[0];
        sw[t] = v;
    }
    __syncthreads();

    int i = blockIdx.x * blockDim.x + threadIdx.x;
    if (i >= N_NODES) return;

    const float4 pf = *(const float4*)(packed + ((size_t)i << 3));       // x0,x1,a0,a1
    const float2 pm = *(const float2*)(packed + ((size_t)i << 3) + 4);   // m0,m1
    float xi0 = pf.x, xi1 = pf.y, a0 = pf.z, a1 = pf.w, m0 = pm.x, m1 = pm.y;

    float mxv[32], smv[32];
    const float4* at = (const float4*)(aggT + ((size_t)i << 6));
#pragma unroll
    for (int q = 0; q < 8; q++) {
        float4 a = at[q];
        mxv[4 * q] = a.x; mxv[4 * q + 1] = a.y; mxv[4 * q + 2] = a.z; mxv[4 * q + 3] = a.w;
        float4 s = at[8 + q];
        smv[4 * q] = s.x; smv[4 * q + 1] = s.y; smv[4 * q + 2] = s.z; smv[4 * q + 3] = s.w;
    }

    float hh[32];
#pragma unroll
    for (int k = 0; k < 24; k++) {
        float v = sw[48 + k] + sw[2 * k] * a0 + sw[2 * k + 1] * a1
                + sw[72 + 2 * k] * xi0 + sw[72 + 2 * k + 1] * xi1;
        hh[k] = fmaxf(v, 0.0f);
    }
#pragma unroll
    for (int k = 0; k < 8; k++) {
        float v = sw[136 + k] + sw[120 + 2 * k] * m0 + sw[120 + 2 * k + 1] * m1
                + sw[144 + 2 * k] * xi0 + sw[144 + 2 * k + 1] * xi1;
        hh[24 + k] = fmaxf(v, 0.0f);
    }

    float h2[16];
#pragma unroll
    for (int j = 0; j < 12; j++) {
        float v = sw[544 + j];
#pragma unroll
        for (int k = 0; k < 32; k++)
            v += smv[k] * sw[160 + j * 32 + k] + hh[k] * sw[556 + j * 32 + k];
        h2[j] = fmaxf(v, 0.0f);
    }
#pragma unroll
    for (int j = 0; j < 4; j++) {
        float v = sw[1068 + j];
#pragma unroll
        for (int k = 0; k < 32; k++)
            v += mxv[k] * sw[940 + j * 32 + k] + hh[k] * sw[1072 + j * 32 + k];
        h2[12 + j] = fmaxf(v, 0.0f);
    }

    float t3[8];
#pragma unroll
    for (int j = 0; j < 8; j++) {
        float v = sw[1328 + j];
#pragma unroll
        for (int k = 0; k < 16; k++) v += h2[k] * sw[1200 + j * 16 + k];
        t3[j] = fmaxf(v, 0.0f);
    }
    float t4[5];
#pragma unroll
    for (int j = 0; j < 5; j++) {
        float v = sw[1376 + j];
#pragma unroll
        for (int k = 0; k < 8; k++) v += t3[k] * sw[1336 + j * 8 + k];
        t4[j] = fmaxf(v, 0.0f);
    }
    float o = sw[1386];
#pragma unroll
    for (int k = 0; k < 5; k++) o += t4[k] * sw[1381 + k];
    out[i] = o;
}

extern "C" void kernel_launch(void* const* d_in, const int* in_sizes, int n_in,
                              void* d_out, int out_size, void* d_ws, size_t ws_size,
                              hipStream_t stream) {
    const float* x     = (const float*)d_in[0];
    const int*   ei    = (const int*)d_in[1];
    const float* norm  = (const float*)d_in[2];
    const float* w1m_l = (const float*)d_in[3];
    const float* b1m   = (const float*)d_in[4];
    const float* w1m_r = (const float*)d_in[5];
    const float* w1x_l = (const float*)d_in[6];
    const float* b1x   = (const float*)d_in[7];
    const float* w1x_r = (const float*)d_in[8];
    const float* w2m_l = (const float*)d_in[9];
    const float* b2m   = (const float*)d_in[10];
    const float* w2m_r = (const float*)d_in[11];
    const float* w2x_l = (const float*)d_in[12];
    const float* b2x   = (const float*)d_in[13];
    const float* w2x_r = (const float*)d_in[14];
    const float* w3    = (const float*)d_in[15];
    const float* b3    = (const float*)d_in[16];
    const float* w4    = (const float*)d_in[17];
    const float* b4    = (const float*)d_in[18];
    const float* w5    = (const float*)d_in[19];
    const float* b5    = (const float*)d_in[20];
    float* out = (float*)d_out;

    // workspace (~58 MB), every buffer fully written -> no memsets
    char* ws = (char*)d_ws;
    int2*  ebuf   = (int2*)ws;                               // 25.6 MB
    float* packed = (float*)(ws + (size_t)N_EDGES * 8);      // NPAD*8*4  = 3.2 MB
    float* aggT   = packed + (size_t)NPAD * 8;               // NPAD*64*4 = 25.6 MB
    int*   nodeBase   = (int*)(aggT + (size_t)NPAD * 64);    // NPAD+1
    int*   bucketBase = nodeBase + NPAD + 1;                 // NBUCK+1
    int*   cntMat     = bucketBase + NBUCK + 1;              // K13_BLOCKS*NBUCK = 1.6 MB
    int*   blockBase  = cntMat + K13_BLOCKS * NBUCK;         // K13_BLOCKS*NBUCK = 1.6 MB

    k1_count    <<<K13_BLOCKS, 1024, 0, stream>>>(ei + N_EDGES, cntMat);
    k2_scan     <<<1, 1024, 0, stream>>>(cntMat, blockBase, bucketBase);
    k3_scatter  <<<K13_BLOCKS, 1024, 0, stream>>>(ei, norm, blockBase, ebuf);
    k3b_sort_agg<<<NBUCK, 256, 0, stream>>>((const float2*)x, bucketBase, ebuf,
                                            nodeBase, packed);
    k5_agg      <<<K5_BLOCKS, 256, 0, stream>>>(packed, ebuf, nodeBase,
                                                w1m_l, b1m, w1m_r, w1x_l, b1x, w1x_r,
                                                aggT);
    k6_final    <<<(N_NODES + 255) / 256, 256, 0, stream>>>(packed, aggT,
                                                w1m_l, b1m, w1m_r, w1x_l, b1x, w1x_r,
                                                w2m_l, b2m, w2m_r, w2x_l, b2x, w2x_r,
                                                w3, b3, w4, b4, w5, b5, out);
}

// Round 12
// 378.951 us; speedup vs baseline: 1.4524x; 1.4524x over previous
//
#include <hip/hip_runtime.h>
#include <cstdint>

#define N_NODES 100000
#define N_EDGES 3200000
#define BSZ     64                // dst nodes per bucket
#define NBUCK   1563              // ceil(N_NODES / 64)
#define NPAD    (NBUCK * BSZ)     // 100032
#define NPAIR   (NPAD / 2)        // 50016 node-pairs for k5
#define SORTCAP 4096              // bucket avg 2048, sigma ~45 -> huge margin
#define K13_BLOCKS 256
#define K13_CHUNK  12500          // 256 * 12500 = 3.2M exactly
#define K5_BLOCKS  1024           // measured best (round 10); latency, not waves, limits
#define K5_WAVES   (K5_BLOCKS * 4)

// ---- float <-> order-preserving unsigned (signed-float max via uint max) ----
__device__ __forceinline__ unsigned flipf(float f) {
    unsigned u = __float_as_uint(f);
    return (u & 0x80000000u) ? ~u : (u | 0x80000000u);   // never returns 0
}
__device__ __forceinline__ float unflipf(unsigned v) {
    unsigned u = (v & 0x80000000u) ? (v & 0x7FFFFFFFu) : ~v;
    return __uint_as_float(u);
}
__device__ __forceinline__ int2 nt_load_rec(const int2* p) {
    unsigned long long v = __builtin_nontemporal_load((const unsigned long long*)p);
    return make_int2((int)(unsigned)(v & 0xFFFFFFFFull), (int)(unsigned)(v >> 32));
}

// ---------------- K1: per-(block,bucket) counts, plain stores, NO global atomics ----------------
__global__ __launch_bounds__(1024) void k1_count(const int* __restrict__ dst,
                                                 int* __restrict__ cntMat) {
    __shared__ int hist[NBUCK];
    for (int t = threadIdx.x; t < NBUCK; t += 1024) hist[t] = 0;
    __syncthreads();
    int e0 = blockIdx.x * K13_CHUNK;
    for (int k = threadIdx.x; k < K13_CHUNK; k += 1024)
        atomicAdd(&hist[__builtin_nontemporal_load(&dst[e0 + k]) >> 6], 1);
    __syncthreads();
    int base = blockIdx.x * NBUCK;
    for (int t = threadIdx.x; t < NBUCK; t += 1024)
        cntMat[base + t] = hist[t];
}

// ---------------- K2a: bucket totals (coalesced, 1563-parallel) ----------------
__global__ __launch_bounds__(256) void k2a_totals(const int* __restrict__ cntMat,
                                                  int* __restrict__ total) {
    int t = blockIdx.x * 256 + threadIdx.x;
    if (t >= NBUCK) return;
    int s = 0;
    for (int b = 0; b < K13_BLOCKS; b++) s += cntMat[b * NBUCK + t];
    total[t] = s;
}

// ---------------- K2b: exclusive scan of 1563 totals -> bucketBase ----------------
__global__ __launch_bounds__(512) void k2b_scan(const int* __restrict__ total,
                                                int* __restrict__ bucketBase) {
    __shared__ int part[512];
    int t = threadIdx.x;
    int base = t * 4;
    int v0 = (base     < NBUCK) ? total[base]     : 0;
    int v1 = (base + 1 < NBUCK) ? total[base + 1] : 0;
    int v2 = (base + 2 < NBUCK) ? total[base + 2] : 0;
    int v3 = (base + 3 < NBUCK) ? total[base + 3] : 0;
    int s = v0 + v1 + v2 + v3;
    part[t] = s;
    __syncthreads();
    for (int off = 1; off < 512; off <<= 1) {
        int u = (t >= off) ? part[t - off] : 0;
        __syncthreads();
        part[t] += u;
        __syncthreads();
    }
    int ex = part[t] - s;
    if (base     < NBUCK) bucketBase[base]     = ex;
    if (base + 1 < NBUCK) bucketBase[base + 1] = ex + v0;
    if (base + 2 < NBUCK) bucketBase[base + 2] = ex + v0 + v1;
    if (base + 3 < NBUCK) bucketBase[base + 3] = ex + v0 + v1 + v2;
    if (t == 511) bucketBase[NBUCK] = part[511];
}

// ---------------- K2c: per-(block,bucket) bases (coalesced, 1563-parallel) ----------------
__global__ __launch_bounds__(256) void k2c_blockbase(const int* __restrict__ cntMat,
                                                     const int* __restrict__ bucketBase,
                                                     int* __restrict__ blockBase) {
    int t = blockIdx.x * 256 + threadIdx.x;
    if (t >= NBUCK) return;
    int run = bucketBase[t];
    for (int b = 0; b < K13_BLOCKS; b++) {
        blockBase[b * NBUCK + t] = run;
        run += cntMat[b * NBUCK + t];
    }
}

// ---------------- K3: SINGLE-PASS scatter (bases precomputed) ----------------
// record: int2 { (src<<6) | (dst&63), bits(norm) }
__global__ __launch_bounds__(1024) void k3_scatter(const int* __restrict__ ei,
                                                   const float* __restrict__ norm,
                                                   const int* __restrict__ blockBase,
                                                   int2* __restrict__ ebuf) {
    __shared__ int lcur[NBUCK];
    int mbase = blockIdx.x * NBUCK;
    for (int t = threadIdx.x; t < NBUCK; t += 1024) lcur[t] = blockBase[mbase + t];
    __syncthreads();
    int e0 = blockIdx.x * K13_CHUNK;
    for (int k = threadIdx.x; k < K13_CHUNK; k += 1024) {
        int e = e0 + k;
        int s = __builtin_nontemporal_load(&ei[e]);
        int d = __builtin_nontemporal_load(&ei[N_EDGES + e]);
        float w = __builtin_nontemporal_load(&norm[e]);
        int r = atomicAdd(&lcur[d >> 6], 1);
        ebuf[r] = make_int2((s << 6) | (d & 63), __float_as_int(w));
    }
}

// ---- K3b: per-bucket counting sort (1 global read, LDS-staged, L2-local scatter-back)
//      + FUSED layer-1 aggregation -> packed row [x0,x1,a0,a1 | x0,x1,m0,m1] (32 B) ----
//      Rewrites records as { src*32 (byte offset into packed), bits(norm) }.
__global__ __launch_bounds__(256) void k3b_sort_agg(
        const float2* __restrict__ x, const int* __restrict__ bucketBase,
        int2* __restrict__ ebuf, int* __restrict__ nodeBase,
        float* __restrict__ packed) {
    __shared__ int2 recs[SORTCAP];           // 32 KB, only big LDS buffer
    __shared__ int cnt[BSZ], off_s[BSZ], cur[BSZ];
    __shared__ float    s_a0[BSZ], s_a1[BSZ];
    __shared__ unsigned s_m0[BSZ], s_m1[BSZ];
    int b = blockIdx.x;
    int beg = bucketBase[b], end = bucketBase[b + 1];
    int n = end - beg;
    if (threadIdx.x < BSZ) {
        cnt[threadIdx.x] = 0;
        s_a0[threadIdx.x] = 0.0f; s_a1[threadIdx.x] = 0.0f;
        s_m0[threadIdx.x] = 0u;   s_m1[threadIdx.x] = 0u;
    }
    __syncthreads();
    // pass 1: single global read -> LDS, count
    for (int k = threadIdx.x; k < n; k += 256) {
        int2 r = ebuf[beg + k];
        recs[k] = r;
        atomicAdd(&cnt[r.x & 63], 1);
    }
    __syncthreads();
    if (threadIdx.x == 0) {
        int a = 0;
        for (int j = 0; j < BSZ; j++) { off_s[j] = a; cur[j] = a; a += cnt[j]; }
    }
    __syncthreads();
    // pass 2: place (scattered write inside bucket range -> L2-absorbed) + aggregate
    for (int k = threadIdx.x; k < n; k += 256) {
        int2 r = recs[k];
        int l = r.x & 63;
        int src = r.x >> 6;
        int p = atomicAdd(&cur[l], 1);
        ebuf[beg + p] = make_int2(src << 5, r.y);        // src*32 byte offset
        float2 xs = x[src];                              // 0.8 MB table, L2-resident
        float w = __int_as_float(r.y);
        atomicAdd(&s_a0[l], xs.x * w);
        atomicAdd(&s_a1[l], xs.y * w);
        atomicMax(&s_m0[l], flipf(xs.x));
        atomicMax(&s_m1[l], flipf(xs.y));
    }
    if (threadIdx.x < BSZ) nodeBase[b * BSZ + threadIdx.x] = beg + off_s[threadIdx.x];
    if (threadIdx.x == BSZ) nodeBase[b * BSZ + BSZ] = end;  // benign same-value race
    __syncthreads();

    int t = threadIdx.x;
    if (t >= BSZ) return;
    int i = b * BSZ + t;
    if (i >= N_NODES) return;
    float2 xi = x[i];
    unsigned m0u = s_m0[t], m1u = s_m1[t];
    float m0 = m0u ? unflipf(m0u) : 0.0f;    // 0 sentinel == empty segment -> 0
    float m1 = m1u ? unflipf(m1u) : 0.0f;
    float4* pk = (float4*)(packed + ((size_t)i << 3));
    pk[0] = make_float4(xi.x, xi.y, s_a0[t], s_a1[t]);   // sub-row for f<24 lanes
    pk[1] = make_float4(xi.x, xi.y, m0, m1);             // sub-row for f>=24 lanes
}

// -------- K5: fused layer-2 MAX+SUM, half-wave/node, software-pipelined recs --------
// Per edge: 1 broadcast rec + 1 broadcast float4 row + ~7 VALU. No atomics.
__global__ __launch_bounds__(256) void k5_agg(
        const float* __restrict__ packed, const int2* __restrict__ ebuf,
        const int* __restrict__ nodeBase,
        const float* __restrict__ w1m_l, const float* __restrict__ b1m,
        const float* __restrict__ w1m_r,
        const float* __restrict__ w1x_l, const float* __restrict__ b1x,
        const float* __restrict__ w1x_r,
        float* __restrict__ aggT) {
    int f = threadIdx.x & 31;
    float c0, c1, c2, c3, c4;
    if (f < 24) {
        c0 = b1m[f];
        c1 = w1m_l[2 * f]; c2 = w1m_l[2 * f + 1];
        c3 = w1m_r[2 * f]; c4 = w1m_r[2 * f + 1];
    } else {
        int g = f - 24;
        c0 = b1x[g];
        c1 = w1x_l[2 * g]; c2 = w1x_l[2 * g + 1];
        c3 = w1x_r[2 * g]; c4 = w1x_r[2 * g + 1];
    }
    int sel = (f < 24) ? 0 : 16;             // byte offset of sub-row
    const char* pbase = (const char*)packed;
    int h = (threadIdx.x >> 5) & 1;
    int wid = blockIdx.x * 4 + (threadIdx.x >> 6);

    for (int p = wid; p < NPAIR; p += K5_WAVES) {
        int i = 2 * p + h;
        int e0 = nodeBase[i], e1 = nodeBase[i + 1];
        float mx = 0.0f, sm = 0.0f;          // relu floor == empty-segment 0
        int e = e0;
        if (e1 - e0 >= 8) {
            int2 rr[8];
#pragma unroll
            for (int j = 0; j < 8; j++) rr[j] = nt_load_rec(&ebuf[e0 + j]);
            for (e = e0 + 8; e + 8 <= e1; e += 8) {
                int2 nx[8];
#pragma unroll
                for (int j = 0; j < 8; j++) nx[j] = nt_load_rec(&ebuf[e + j]);
#pragma unroll
                for (int j = 0; j < 8; j++) {
                    float4 q = *(const float4*)(pbase + (size_t)(unsigned)(rr[j].x + sel));
                    float v = fmaxf(c0 + c3 * q.x + c4 * q.y + c1 * q.z + c2 * q.w, 0.0f);
                    mx = fmaxf(mx, v);
                    sm = fmaf(__int_as_float(rr[j].y), v, sm);
                }
#pragma unroll
                for (int j = 0; j < 8; j++) rr[j] = nx[j];
            }
#pragma unroll
            for (int j = 0; j < 8; j++) {
                float4 q = *(const float4*)(pbase + (size_t)(unsigned)(rr[j].x + sel));
                float v = fmaxf(c0 + c3 * q.x + c4 * q.y + c1 * q.z + c2 * q.w, 0.0f);
                mx = fmaxf(mx, v);
                sm = fmaf(__int_as_float(rr[j].y), v, sm);
            }
        }
        for (; e < e1; e++) {
            int2 r = nt_load_rec(&ebuf[e]);
            float4 q = *(const float4*)(pbase + (size_t)(unsigned)(r.x + sel));
            float v = fmaxf(c0 + c3 * q.x + c4 * q.y + c1 * q.z + c2 * q.w, 0.0f);
            mx = fmaxf(mx, v);
            sm = fmaf(__int_as_float(r.y), v, sm);
        }
        float* o = aggT + ((size_t)i << 6);
        o[f] = mx;
        o[32 + f] = sm;
    }
}

// -------- K6: node-parallel final: W2m_l@sm + node2 + MLP head -> out --------
__global__ __launch_bounds__(256) void k6_final(
        const float* __restrict__ packed, const float* __restrict__ aggT,
        const float* __restrict__ w1m_l, const float* __restrict__ b1m,
        const float* __restrict__ w1m_r,
        const float* __restrict__ w1x_l, const float* __restrict__ b1x,
        const float* __restrict__ w1x_r,
        const float* __restrict__ w2m_l,
        const float* __restrict__ b2m, const float* __restrict__ w2m_r,
        const float* __restrict__ w2x_l, const float* __restrict__ b2x,
        const float* __restrict__ w2x_r,
        const float* __restrict__ w3, const float* __restrict__ b3,
        const float* __restrict__ w4, const float* __restrict__ b4,
        const float* __restrict__ w5, const float* __restrict__ b5,
        float* __restrict__ out) {
    __shared__ float sw[1387];
    for (int t = threadIdx.x; t < 1387; t += 256) {
        float v;
        if (t < 48)        v = w1m_l[t];
        else if (t < 72)   v = b1m[t - 48];
        else if (t < 120)  v = w1m_r[t - 72];
        else if (t < 136)  v = w1x_l[t - 120];
        else if (t < 144)  v = b1x[t - 136];
        else if (t < 160)  v = w1x_r[t - 144];
        else if (t < 544)  v = w2m_l[t - 160];
        else if (t < 556)  v = b2m[t - 544];
        else if (t < 940)  v = w2m_r[t - 556];
        else if (t < 1068) v = w2x_l[t - 940];
        else if (t < 1072) v = b2x[t - 1068];
        else if (t < 1200) v = w2x_r[t - 1072];
        else if (t < 1328) v = w3[t - 1200];
        else if (t < 1336) v = b3[t - 1328];
        else if (t < 1376) v = w4[t - 1336];
        else if (t < 1381) v = b4[t - 1376];
        else if (t < 1386) v = w5[t - 1381];
        else               v = b5[0];
        sw[t] = v;
    }
    __syncthreads();

    int i = blockIdx.x * blockDim.x + threadIdx.x;
    if (i >= N_NODES) return;

    const float* row = packed + ((size_t)i << 3);
    float4 pf = *(const float4*)row;                     // x0,x1,a0,a1
    float2 pm = *(const float2*)(row + 6);               // m0,m1
    float xi0 = pf.x, xi1 = pf.y, a0 = pf.z, a1 = pf.w, m0 = pm.x, m1 = pm.y;

    float mxv[32], smv[32];
    const float4* at = (const float4*)(aggT + ((size_t)i << 6));
#pragma unroll
    for (int q = 0; q < 8; q++) {
        float4 a = at[q];
        mxv[4 * q] = a.x; mxv[4 * q + 1] = a.y; mxv[4 * q + 2] = a.z; mxv[4 * q + 3] = a.w;
        float4 s = at[8 + q];
        smv[4 * q] = s.x; smv[4 * q + 1] = s.y; smv[4 * q + 2] = s.z; smv[4 * q + 3] = s.w;
    }

    float hh[32];
#pragma unroll
    for (int k = 0; k < 24; k++) {
        float v = sw[48 + k] + sw[2 * k] * a0 + sw[2 * k + 1] * a1
                + sw[72 + 2 * k] * xi0 + sw[72 + 2 * k + 1] * xi1;
        hh[k] = fmaxf(v, 0.0f);
    }
#pragma unroll
    for (int k = 0; k < 8; k++) {
        float v = sw[136 + k] + sw[120 + 2 * k] * m0 + sw[120 + 2 * k + 1] * m1
                + sw[144 + 2 * k] * xi0 + sw[144 + 2 * k + 1] * xi1;
        hh[24 + k] = fmaxf(v, 0.0f);
    }

    float h2[16];
#pragma unroll
    for (int j = 0; j < 12; j++) {
        float v = sw[544 + j];
#pragma unroll
        for (int k = 0; k < 32; k++)
            v += smv[k] * sw[160 + j * 32 + k] + hh[k] * sw[556 + j * 32 + k];
        h2[j] = fmaxf(v, 0.0f);
    }
#pragma unroll
    for (int j = 0; j < 4; j++) {
        float v = sw[1068 + j];
#pragma unroll
        for (int k = 0; k < 32; k++)
            v += mxv[k] * sw[940 + j * 32 + k] + hh[k] * sw[1072 + j * 32 + k];
        h2[12 + j] = fmaxf(v, 0.0f);
    }

    float t3[8];
#pragma unroll
    for (int j = 0; j < 8; j++) {
        float v = sw[1328 + j];
#pragma unroll
        for (int k = 0; k < 16; k++) v += h2[k] * sw[1200 + j * 16 + k];
        t3[j] = fmaxf(v, 0.0f);
    }
    float t4[5];
#pragma unroll
    for (int j = 0; j < 5; j++) {
        float v = sw[1376 + j];
#pragma unroll
        for (int k = 0; k < 8; k++) v += t3[k] * sw[1336 + j * 8 + k];
        t4[j] = fmaxf(v, 0.0f);
    }
    float o = sw[1386];
#pragma unroll
    for (int k = 0; k < 5; k++) o += t4[k] * sw[1381 + k];
    out[i] = o;
}

extern "C" void kernel_launch(void* const* d_in, const int* in_sizes, int n_in,
                              void* d_out, int out_size, void* d_ws, size_t ws_size,
                              hipStream_t stream) {
    const float* x     = (const float*)d_in[0];
    const int*   ei    = (const int*)d_in[1];
    const float* norm  = (const float*)d_in[2];
    const float* w1m_l = (const float*)d_in[3];
    const float* b1m   = (const float*)d_in[4];
    const float* w1m_r = (const float*)d_in[5];
    const float* w1x_l = (const float*)d_in[6];
    const float* b1x   = (const float*)d_in[7];
    const float* w1x_r = (const float*)d_in[8];
    const float* w2m_l = (const float*)d_in[9];
    const float* b2m   = (const float*)d_in[10];
    const float* w2m_r = (const float*)d_in[11];
    const float* w2x_l = (const float*)d_in[12];
    const float* b2x   = (const float*)d_in[13];
    const float* w2x_r = (const float*)d_in[14];
    const float* w3    = (const float*)d_in[15];
    const float* b3    = (const float*)d_in[16];
    const float* w4    = (const float*)d_in[17];
    const float* b4    = (const float*)d_in[18];
    const float* w5    = (const float*)d_in[19];
    const float* b5    = (const float*)d_in[20];
    float* out = (float*)d_out;

    // workspace (~58 MB), every buffer fully written -> no memsets
    char* ws = (char*)d_ws;
    int2*  ebuf   = (int2*)ws;                               // 25.6 MB
    float* packed = (float*)(ws + (size_t)N_EDGES * 8);      // NPAD*8*4  = 3.2 MB
    float* aggT   = packed + (size_t)NPAD * 8;               // NPAD*64*4 = 25.6 MB
    int*   nodeBase   = (int*)(aggT + (size_t)NPAD * 64);    // NPAD+1
    int*   bucketBase = nodeBase + NPAD + 1;                 // NBUCK+1
    int*   total      = bucketBase + NBUCK + 1;              // NBUCK
    int*   cntMat     = total + NBUCK;                       // 256*NBUCK = 1.6 MB
    int*   blockBase  = cntMat + K13_BLOCKS * NBUCK;         // 256*NBUCK = 1.6 MB

    k1_count    <<<K13_BLOCKS, 1024, 0, stream>>>(ei + N_EDGES, cntMat);
    k2a_totals  <<<(NBUCK + 255) / 256, 256, 0, stream>>>(cntMat, total);
    k2b_scan    <<<1, 512, 0, stream>>>(total, bucketBase);
    k2c_blockbase<<<(NBUCK + 255) / 256, 256, 0, stream>>>(cntMat, bucketBase, blockBase);
    k3_scatter  <<<K13_BLOCKS, 1024, 0, stream>>>(ei, norm, blockBase, ebuf);
    k3b_sort_agg<<<NBUCK, 256, 0, stream>>>((const float2*)x, bucketBase, ebuf,
                                            nodeBase, packed);
    k5_agg      <<<K5_BLOCKS, 256, 0, stream>>>(packed, ebuf, nodeBase,
                                                w1m_l, b1m, w1m_r, w1x_l, b1x, w1x_r,
                                                aggT);
    k6_final    <<<(N_NODES + 255) / 256, 256, 0, stream>>>(packed, aggT,
                                                w1m_l, b1m, w1m_r, w1x_l, b1x, w1x_r,
                                                w2m_l, b2m, w2m_r, w2x_l, b2x, w2x_r,
                                                w3, b3, w4, b4, w5, b5, out);
}